// Round 1
// baseline (731.259 us; speedup 1.0000x reference)
//
#include <hip/hip_runtime.h>
#include <math.h>

#define BB 16384
#define DD 4096
#define EE 64
#define TK 8
#define KT 64            // k-tile depth
#define RT 64            // rows per block
#define XS_STRIDE 68     // 64 + 4 pad: bank stride 4 per row -> conflict-free, 16B aligned
#define LS_STRIDE 132    // 128 + 4 pad, 16B aligned

__global__ __launch_bounds__(256, 1)
void moe_fused(const float* __restrict__ x,
               const float* __restrict__ wg,
               const float* __restrict__ wn,
               const float* __restrict__ noise,
               float* __restrict__ gates,
               float* __restrict__ load)
{
    __shared__ float Xs[RT * XS_STRIDE];   // 17408 B
    __shared__ float Ws[KT * 128];         // 32768 B
    __shared__ float Ls[RT * LS_STRIDE];   // 33792 B : full 64x128 logits tile
    __shared__ float red[4 * 64];

    const int tid = threadIdx.x;
    const int cg  = tid >> 3;   // 0..31 : column group (4 cols)
    const int rw  = tid & 7;    // 0..7  : row-within-group
    const int rb  = blockIdx.x * RT;

    float acc[8][4];
#pragma unroll
    for (int j = 0; j < 8; ++j)
#pragma unroll
        for (int c = 0; c < 4; ++c) acc[j][c] = 0.f;

    // ---- GEMM: C[64][128] = X[64][4096] @ [wg | wn] ----
    for (int t = 0; t < DD / KT; ++t) {
        const int d0 = t * KT;
        // stage X tile: 64 rows x 64 k = 1024 float4, 4 per thread
#pragma unroll
        for (int i = 0; i < 4; ++i) {
            int f   = tid + i * 256;
            int row = f >> 4;          // 0..63
            int k4  = f & 15;
            float4 v = *(const float4*)&x[(size_t)(rb + row) * DD + d0 + k4 * 4];
            *(float4*)&Xs[row * XS_STRIDE + k4 * 4] = v;
        }
        // stage W tiles: wg 64x64 and wn 64x64 -> Ws[k][0..63], Ws[k][64..127]
#pragma unroll
        for (int i = 0; i < 4; ++i) {
            int f  = tid + i * 256;
            int k  = f >> 4;           // 0..63
            int e4 = f & 15;
            float4 vg = *(const float4*)&wg[(size_t)(d0 + k) * EE + e4 * 4];
            float4 vn = *(const float4*)&wn[(size_t)(d0 + k) * EE + e4 * 4];
            *(float4*)&Ws[k * 128 + e4 * 4]      = vg;
            *(float4*)&Ws[k * 128 + 64 + e4 * 4] = vn;
        }
        __syncthreads();

#pragma unroll 4
        for (int kk4 = 0; kk4 < KT / 4; ++kk4) {
            float4 xv[8];
#pragma unroll
            for (int j = 0; j < 8; ++j)
                xv[j] = *(const float4*)&Xs[(j * 8 + rw) * XS_STRIDE + kk4 * 4];
            float4 wv[4];
#pragma unroll
            for (int kk = 0; kk < 4; ++kk)
                wv[kk] = *(const float4*)&Ws[(kk4 * 4 + kk) * 128 + cg * 4];
#pragma unroll
            for (int kk = 0; kk < 4; ++kk) {
#pragma unroll
                for (int j = 0; j < 8; ++j) {
                    float xs = ((const float*)&xv[j])[kk];
                    acc[j][0] = fmaf(xs, wv[kk].x, acc[j][0]);
                    acc[j][1] = fmaf(xs, wv[kk].y, acc[j][1]);
                    acc[j][2] = fmaf(xs, wv[kk].z, acc[j][2]);
                    acc[j][3] = fmaf(xs, wv[kk].w, acc[j][3]);
                }
            }
        }
        __syncthreads();
    }

    // ---- spill logits tile to LDS (row = j*8+rw, cols cg*4..cg*4+3) ----
#pragma unroll
    for (int j = 0; j < 8; ++j) {
        float4 v;
        v.x = acc[j][0]; v.y = acc[j][1]; v.z = acc[j][2]; v.w = acc[j][3];
        *(float4*)&Ls[(j * 8 + rw) * LS_STRIDE + cg * 4] = v;
    }
    __syncthreads();

    // ---- epilogue: wave-per-row, lane = expert ----
    const int wid  = tid >> 6;   // 0..3
    const int lane = tid & 63;
    float loadAcc = 0.f;

    for (int rr = 0; rr < 16; ++rr) {
        const int row = wid * 16 + rr;
        const float clean = Ls[row * LS_STRIDE + lane];
        const float rawn  = Ls[row * LS_STRIDE + 64 + lane];
        const float nz    = noise[(size_t)(rb + row) * EE + lane];

        // softplus (stable) + eps
        const float sp = fmaxf(rawn, 0.f) + log1pf(expf(-fabsf(rawn)));
        const float sd = sp + 0.01f;
        const float noisy = clean + nz * sd;

        // softmax over 64 experts (wave-wide)
        float m = noisy;
#pragma unroll
        for (int off = 32; off; off >>= 1) m = fmaxf(m, __shfl_xor(m, off));
        const float ex = expf(noisy - m);
        float s = ex;
#pragma unroll
        for (int off = 32; off; off >>= 1) s += __shfl_xor(s, off);
        const float p = ex / s;

        // iterative top-9 (argmax with lowest-index tie-break = lax.top_k)
        float cur = p;
        int selrank = -1;
        float v[9];
#pragma unroll
        for (int j = 0; j < 9; ++j) {
            float bv = cur;
            int   bi = lane;
#pragma unroll
            for (int off = 32; off; off >>= 1) {
                const float ov = __shfl_xor(bv, off);
                const int   oi = __shfl_xor(bi, off);
                if (ov > bv || (ov == bv && oi < bi)) { bv = ov; bi = oi; }
            }
            v[j] = bv;
            if (lane == bi) { cur = -1.f; if (j < TK) selrank = j; }
        }

        // gates = softmax over top-8 probs, scattered to selected lanes
        float denom = 0.f;
#pragma unroll
        for (int j = 0; j < TK; ++j) denom += expf(v[j] - v[0]);
        const float gate = (selrank >= 0) ? (expf(p - v[0]) / denom) : 0.f;
        gates[(size_t)(rb + row) * EE + lane] = gate;

        // load contribution (reference compares logits against prob thresholds)
        const float thr_in  = v[8];
        const float thr_out = v[7];
        const bool  is_in   = noisy > thr_in;
        const float a = (clean - (is_in ? thr_in : thr_out)) / sd;
        loadAcc += 0.5f * (1.f + erff(a * 0.70710678118654752f));
    }

    // reduce load across the 4 waves, then one atomicAdd per expert per block
    red[wid * 64 + lane] = loadAcc;
    __syncthreads();
    if (tid < 64) {
        const float sum = red[tid] + red[64 + tid] + red[128 + tid] + red[192 + tid];
        atomicAdd(&load[tid], sum);
    }
}

extern "C" void kernel_launch(void* const* d_in, const int* in_sizes, int n_in,
                              void* d_out, int out_size, void* d_ws, size_t ws_size,
                              hipStream_t stream)
{
    const float* x     = (const float*)d_in[0];
    const float* wg    = (const float*)d_in[1];
    const float* wn    = (const float*)d_in[2];
    const float* noise = (const float*)d_in[3];
    float* gates = (float*)d_out;
    float* load  = (float*)d_out + (size_t)BB * EE;

    // d_out is poisoned 0xAA before every timed launch: zero the load slot
    hipMemsetAsync(load, 0, EE * sizeof(float), stream);

    dim3 grid(BB / RT), block(256);
    hipLaunchKernelGGL(moe_fused, grid, block, 0, stream, x, wg, wn, noise, gates, load);
}

// Round 2
// 481.333 us; speedup vs baseline: 1.5192x; 1.5192x over previous
//
#include <hip/hip_runtime.h>
#include <math.h>

#define BB 16384
#define DD 4096
#define EE 64
#define TK 8

// ext-vector types for MFMA (per guide: short8 for bf16 A/B frags, float4 C/D)
typedef __attribute__((ext_vector_type(8))) short s16x8;
typedef __attribute__((ext_vector_type(4))) float f32x4;

__device__ inline unsigned pack_hi2(float a, float b) {
    // two bf16 (truncated from fp32) packed into one u32: a -> low16, b -> high16
    return (__float_as_uint(a) >> 16) | (__float_as_uint(b) & 0xFFFF0000u);
}
__device__ inline float hi_part(float a) {
    return __uint_as_float(__float_as_uint(a) & 0xFFFF0000u);
}

// ---------------------------------------------------------------------------
// prep: convert [wg | wn] fp32 -> bf16 hi/lo in MFMA B-fragment order in ws.
// ws layout: [kchunk(64)][sub(2)][prec(2)][ntile(8)][lane(64)][16B]
//   lane = q*16 + (n&15), slot j = k&7, k_in_chunk = sub*32 + q*8 + j
// One block per 64-k chunk.
// ---------------------------------------------------------------------------
__global__ __launch_bounds__(256, 1)
void prep_w(const float* __restrict__ wg, const float* __restrict__ wn,
            char* __restrict__ wsB)
{
    __shared__ float Wtmp[64 * 132];   // [k_in_chunk][n 0..127], stride 132
    const int t  = threadIdx.x;
    const int kc = blockIdx.x;

    // load 64 k-rows x 64 cols of each matrix (coalesced float4)
#pragma unroll
    for (int i = 0; i < 8; ++i) {
        int fid = t + i * 256;        // 0..2047
        int m   = fid >> 10;          // 0: wg, 1: wn
        int id  = fid & 1023;         // kk*16 + n4
        int kk  = id >> 4;
        int n4  = id & 15;
        const float* src = (m ? wn : wg) + (size_t)(kc * 64 + kk) * EE + n4 * 4;
        float4 v = *(const float4*)src;
        *(float4*)&Wtmp[kk * 132 + m * 64 + n4 * 4] = v;
    }
    __syncthreads();

    // assemble fragment slots; consecutive threads -> consecutive 16B writes
#pragma unroll
    for (int i = 0; i < 4; ++i) {
        int id  = t + i * 256;        // 0..1023 = sub*512 + nt*64 + ln
        int sub = id >> 9;
        int nt  = (id >> 6) & 7;
        int ln  = id & 63;
        int n   = nt * 16 + (ln & 15);
        int k0  = sub * 32 + (ln >> 4) * 8;
        float f[8];
#pragma unroll
        for (int j = 0; j < 8; ++j) f[j] = Wtmp[(k0 + j) * 132 + n];
        uint4 h, l;
        h.x = pack_hi2(f[0], f[1]); h.y = pack_hi2(f[2], f[3]);
        h.z = pack_hi2(f[4], f[5]); h.w = pack_hi2(f[6], f[7]);
        l.x = pack_hi2(f[0] - hi_part(f[0]), f[1] - hi_part(f[1]));
        l.y = pack_hi2(f[2] - hi_part(f[2]), f[3] - hi_part(f[3]));
        l.z = pack_hi2(f[4] - hi_part(f[4]), f[5] - hi_part(f[5]));
        l.w = pack_hi2(f[6] - hi_part(f[6]), f[7] - hi_part(f[7]));
        size_t base = (size_t)kc * 32768;
        *(uint4*)(wsB + base + (size_t)(((sub * 2 + 0) * 8 + nt) * 64 + ln) * 16) = h;
        *(uint4*)(wsB + base + (size_t)(((sub * 2 + 1) * 8 + nt) * 64 + ln) * 16) = l;
    }
}

// ---------------------------------------------------------------------------
// main: 256 blocks x 512 threads; block = 64 rows, full K=4096, all 128 cols.
// 8 waves as (wm 0..3) x (wn 0..1); wave tile 16m x 64n; bf16x2 split MFMA.
// ---------------------------------------------------------------------------
__global__ __launch_bounds__(512, 1)
void moe_mfma(const float* __restrict__ x,
              const float* __restrict__ noise,
              const char* __restrict__ wsB,
              float* __restrict__ gates,
              float* __restrict__ load)
{
    __shared__ uint4 Afrag[1024];      // [sub2][prec2][mtile4][lane64] : 16 KB
    __shared__ uint4 Bfrag[2048];      // [sub2][prec2][ntile8][lane64] : 32 KB
    __shared__ float Ls[64 * 132];     // logits tile for epilogue      : 33 KB
    __shared__ float red[512];

    const int tid  = threadIdx.x;
    const int w    = tid >> 6;
    const int lane = tid & 63;
    const int wm   = w >> 1;           // m-tile of this wave (rows wm*16..+15)
    const int wn   = w & 1;            // n-half (cols wn*64..+63)
    const int rb   = blockIdx.x * 64;

    // staging assignment: 8 threads per row, one 8-k group each
    const int srow  = tid >> 3;        // 0..63
    const int skg   = tid & 7;         // k-group within 64-chunk
    const int ssub  = skg >> 2;
    const int sq    = skg & 3;
    const int slane = sq * 16 + (srow & 15);
    const int smt   = srow >> 4;
    const int aoff_hi = ((ssub * 2 + 0) * 4 + smt) * 64 + slane;
    const int aoff_lo = ((ssub * 2 + 1) * 4 + smt) * 64 + slane;
    const float* xrow = x + (size_t)(rb + srow) * DD + skg * 8;

    f32x4 acc[4];
#pragma unroll
    for (int nt = 0; nt < 4; ++nt) acc[nt] = (f32x4){0.f, 0.f, 0.f, 0.f};

    for (int ch = 0; ch < DD / 64; ++ch) {
        // x global loads (issued first, latency overlaps B DMA issue)
        float4 v0 = *(const float4*)(xrow + ch * 64);
        float4 v1 = *(const float4*)(xrow + ch * 64 + 4);

        // B: direct global->LDS DMA, fragment-ordered, 4x 1KB per wave
        const char* gB = wsB + (size_t)ch * 32768;
#pragma unroll
        for (int i = 0; i < 4; ++i) {
            const int si = w * 4 + i;
            __builtin_amdgcn_global_load_lds(
                (const __attribute__((address_space(1))) unsigned int*)(gB + (size_t)si * 1024 + lane * 16),
                (__attribute__((address_space(3))) unsigned int*)&Bfrag[si * 64],
                16, 0, 0);
        }

        // A: fp32 -> bf16 hi/lo split, write fragment slots
        uint4 h, l;
        h.x = pack_hi2(v0.x, v0.y); h.y = pack_hi2(v0.z, v0.w);
        h.z = pack_hi2(v1.x, v1.y); h.w = pack_hi2(v1.z, v1.w);
        l.x = pack_hi2(v0.x - hi_part(v0.x), v0.y - hi_part(v0.y));
        l.y = pack_hi2(v0.z - hi_part(v0.z), v0.w - hi_part(v0.w));
        l.z = pack_hi2(v1.x - hi_part(v1.x), v1.y - hi_part(v1.y));
        l.w = pack_hi2(v1.z - hi_part(v1.z), v1.w - hi_part(v1.w));
        Afrag[aoff_hi] = h;
        Afrag[aoff_lo] = l;
        __syncthreads();

#pragma unroll
        for (int sub = 0; sub < 2; ++sub) {
            const s16x8 ah = *(const s16x8*)&Afrag[((sub * 2 + 0) * 4 + wm) * 64 + lane];
            const s16x8 al = *(const s16x8*)&Afrag[((sub * 2 + 1) * 4 + wm) * 64 + lane];
#pragma unroll
            for (int nt = 0; nt < 4; ++nt) {
                const s16x8 bh = *(const s16x8*)&Bfrag[((sub * 2 + 0) * 8 + wn * 4 + nt) * 64 + lane];
                const s16x8 bl = *(const s16x8*)&Bfrag[((sub * 2 + 1) * 8 + wn * 4 + nt) * 64 + lane];
                acc[nt] = __builtin_amdgcn_mfma_f32_16x16x32_bf16(ah, bh, acc[nt], 0, 0, 0);
                acc[nt] = __builtin_amdgcn_mfma_f32_16x16x32_bf16(ah, bl, acc[nt], 0, 0, 0);
                acc[nt] = __builtin_amdgcn_mfma_f32_16x16x32_bf16(al, bh, acc[nt], 0, 0, 0);
            }
        }
        __syncthreads();
    }

    // spill accumulators to Ls: C/D layout col=lane&15, row=(lane>>4)*4+r
    const int q4 = lane >> 4, cc = lane & 15;
#pragma unroll
    for (int nt = 0; nt < 4; ++nt)
#pragma unroll
        for (int r = 0; r < 4; ++r)
            Ls[(wm * 16 + q4 * 4 + r) * 132 + wn * 64 + nt * 16 + cc] = acc[nt][r];
    __syncthreads();

    // ---- epilogue: wave-per-row (8 rows per wave), lane = expert ----
    float loadAcc = 0.f;
    for (int rr = 0; rr < 8; ++rr) {
        const int row = w * 8 + rr;
        const float clean = Ls[row * 132 + lane];
        const float rawn  = Ls[row * 132 + 64 + lane];
        const float nz    = noise[(size_t)(rb + row) * EE + lane];

        const float sp = fmaxf(rawn, 0.f) + log1pf(expf(-fabsf(rawn)));
        const float sd = sp + 0.01f;
        const float noisy = clean + nz * sd;

        float m = noisy;
#pragma unroll
        for (int off = 32; off; off >>= 1) m = fmaxf(m, __shfl_xor(m, off));
        const float ex = expf(noisy - m);
        float s = ex;
#pragma unroll
        for (int off = 32; off; off >>= 1) s += __shfl_xor(s, off);
        const float p = ex / s;

        float cur = p;
        int selrank = -1;
        float v[9];
#pragma unroll
        for (int j = 0; j < 9; ++j) {
            float bv = cur;
            int   bi = lane;
#pragma unroll
            for (int off = 32; off; off >>= 1) {
                const float ov = __shfl_xor(bv, off);
                const int   oi = __shfl_xor(bi, off);
                if (ov > bv || (ov == bv && oi < bi)) { bv = ov; bi = oi; }
            }
            v[j] = bv;
            if (lane == bi) { cur = -1.f; if (j < TK) selrank = j; }
        }

        float denom = 0.f;
#pragma unroll
        for (int j = 0; j < TK; ++j) denom += expf(v[j] - v[0]);
        const float gate = (selrank >= 0) ? (expf(p - v[0]) / denom) : 0.f;
        gates[(size_t)(rb + row) * EE + lane] = gate;

        const float thr_in  = v[8];
        const float thr_out = v[7];
        const bool  is_in   = noisy > thr_in;
        const float a = (clean - (is_in ? thr_in : thr_out)) / sd;
        loadAcc += 0.5f * (1.f + erff(a * 0.70710678118654752f));
    }

    red[w * 64 + lane] = loadAcc;
    __syncthreads();
    if (tid < 64) {
        float s = 0.f;
#pragma unroll
        for (int i = 0; i < 8; ++i) s += red[i * 64 + tid];
        atomicAdd(&load[tid], s);
    }
}

extern "C" void kernel_launch(void* const* d_in, const int* in_sizes, int n_in,
                              void* d_out, int out_size, void* d_ws, size_t ws_size,
                              hipStream_t stream)
{
    const float* x     = (const float*)d_in[0];
    const float* wg    = (const float*)d_in[1];
    const float* wn    = (const float*)d_in[2];
    const float* noise = (const float*)d_in[3];
    float* gates = (float*)d_out;
    float* load  = (float*)d_out + (size_t)BB * EE;
    char*  wsB   = (char*)d_ws;   // needs 2 MB

    hipMemsetAsync(load, 0, EE * sizeof(float), stream);
    hipLaunchKernelGGL(prep_w, dim3(DD / 64), dim3(256), 0, stream, wg, wn, wsB);
    hipLaunchKernelGGL(moe_mfma, dim3(BB / 64), dim3(512), 0, stream,
                       x, noise, wsB, gates, load);
}